// Round 15
// baseline (197.771 us; speedup 1.0000x reference)
//
#include <hip/hip_runtime.h>

constexpr int NN  = 50000;
constexpr int NE  = 1600000;
constexpr int CIN = 384;
constexpr int CH  = 128;
constexpr int CO  = 64;

constexpr int NB = (NN + 255) / 256;              // 196 dst-buckets of 256 nodes
constexpr int BUCKET_CAP = 16384;                 // append region per bucket (mean 8163)
constexpr int SCAT_EPB     = 4096;                // 256 thr * 16 edges
constexpr int SCAT_BLOCKS  = (NE + SCAT_EPB - 1) / SCAT_EPB;     // 391
constexpr int G1_TILES     = (NN + 127) / 128;    // 391 blocks of 128 rows

typedef __attribute__((ext_vector_type(8))) short short8;
typedef __attribute__((ext_vector_type(4))) float f32x4;

// ---------------- bf16 helpers ----------------

__device__ inline unsigned short f2bf(float f) {
    union { float f; unsigned int u; } v; v.f = f;
    unsigned int u = v.u + 0x7FFFu + ((v.u >> 16) & 1u);   // round-to-nearest-even
    return (unsigned short)(u >> 16);
}
__device__ inline float bf2f(unsigned short h) { return __uint_as_float((unsigned int)h << 16); }
__device__ inline float bflo(unsigned int u) { return __uint_as_float(u << 16); }
__device__ inline float bfhi(unsigned int u) { return __uint_as_float(u & 0xFFFF0000u); }

// ---------------- W1 transpose + hi/lo bf16 split + cursor init ----------------

__global__ __launch_bounds__(256) void wprep(const float* __restrict__ W1,
                                             unsigned short* __restrict__ W1t_hi,
                                             unsigned short* __restrict__ W1t_lo,
                                             int* __restrict__ bucket_cursor) {
    int i = blockIdx.x * 256 + threadIdx.x;
    if (blockIdx.x == 0 && threadIdx.x < NB)
        bucket_cursor[threadIdx.x] = threadIdx.x * BUCKET_CAP;
    if (i < CIN * CH) {
        int k = i / CH, c = i % CH;
        float v = W1[i];
        unsigned short h = f2bf(v);
        W1t_hi[c * CIN + k] = h;
        W1t_lo[c * CIN + k] = f2bf(v - bf2f(h));
    }
}

// ---------------- fused MFMA-GEMM1 + bucketed edge scatter (r12 sequential roles) ----------------

__global__ __launch_bounds__(256) void fused_gemm1_scatter(const int* __restrict__ src,
                                                           const int* __restrict__ dst,
                                                           int* __restrict__ bucket_cursor,
                                                           unsigned int* __restrict__ pairs,
                                                           const float* __restrict__ X,
                                                           const unsigned short* __restrict__ Wt_hi,
                                                           const unsigned short* __restrict__ Wt_lo,
                                                           unsigned short* __restrict__ Hb) {
    __shared__ unsigned short xs_hi[128][40];   // [row][k], stride 40 -> 2-way bank alias (free)
    __shared__ unsigned short xs_lo[128][40];
    __shared__ unsigned short ws_hi[128][40];   // [col][k]
    __shared__ unsigned short ws_lo[128][40];
    __shared__ int hist[NB];
    __shared__ int base_s[NB];

    int tid = threadIdx.x;
    if (blockIdx.x < SCAT_BLOCKS) {
        int e0 = blockIdx.x * SCAT_EPB;
        for (int i = tid; i < NB; i += 256) hist[i] = 0;
        __syncthreads();
        int key[16];
        unsigned int pay[16];
        #pragma unroll
        for (int k = 0; k < 16; ++k) {
            int e = e0 + k * 256 + tid;
            if (e < NE) {
                int s = src[e], d = dst[e];
                int b = d >> 8;
                int pos = atomicAdd(&hist[b], 1);
                key[k] = b | (pos << 8);
                pay[k] = (unsigned int)s | ((unsigned int)(d & 255) << 16);
            } else {
                key[k] = -1;
            }
        }
        __syncthreads();
        for (int i = tid; i < NB; i += 256)
            base_s[i] = hist[i] ? atomicAdd(&bucket_cursor[i], hist[i]) : 0;
        __syncthreads();
        #pragma unroll
        for (int k = 0; k < 16; ++k) {
            if (key[k] >= 0) {
                int b = key[k] & 255, pos = key[k] >> 8;
                pairs[base_s[b] + pos] = pay[k];
            }
        }
        return;
    }

    // ---- GEMM1: 128 rows x 128 cols per block, 4 waves x (32r x 128c) ----
    int wid = tid >> 6, lane = tid & 63;
    int row0 = (blockIdx.x - SCAT_BLOCKS) * 128;
    f32x4 acc[2][8] = {};

    int xrow = tid >> 1, xc = (tid & 1) * 16;
    int grow = row0 + xrow;
    int wcol = tid >> 2, wko = (tid & 3) * 8;

    float xf[16];
    short8 pwh0, pwl0, pwh1, pwl1;

    auto loadX = [&](int k0) {
        if (grow < NN) {
            const float4* p = reinterpret_cast<const float4*>(X + (size_t)grow * CIN + k0 + xc);
            float4 v0 = p[0], v1 = p[1], v2 = p[2], v3 = p[3];
            xf[0]=v0.x; xf[1]=v0.y; xf[2]=v0.z; xf[3]=v0.w;
            xf[4]=v1.x; xf[5]=v1.y; xf[6]=v1.z; xf[7]=v1.w;
            xf[8]=v2.x; xf[9]=v2.y; xf[10]=v2.z; xf[11]=v2.w;
            xf[12]=v3.x; xf[13]=v3.y; xf[14]=v3.z; xf[15]=v3.w;
        } else {
            #pragma unroll
            for (int i = 0; i < 16; ++i) xf[i] = 0.f;
        }
    };
    auto loadW = [&](int k0) {
        pwh0 = *reinterpret_cast<const short8*>(Wt_hi + (size_t)wcol * CIN + k0 + wko);
        pwl0 = *reinterpret_cast<const short8*>(Wt_lo + (size_t)wcol * CIN + k0 + wko);
        pwh1 = *reinterpret_cast<const short8*>(Wt_hi + (size_t)(wcol + 64) * CIN + k0 + wko);
        pwl1 = *reinterpret_cast<const short8*>(Wt_lo + (size_t)(wcol + 64) * CIN + k0 + wko);
    };

    loadX(0); loadW(0);
    for (int k0 = 0; k0 < CIN; k0 += 32) {
        // convert + LDS write from prefetched regs
        {
            short8 vh0, vh1, vl0, vl1;
            #pragma unroll
            for (int i = 0; i < 8; ++i) {
                unsigned short h = f2bf(xf[i]);
                vh0[i] = (short)h; vl0[i] = (short)f2bf(xf[i] - bf2f(h));
            }
            #pragma unroll
            for (int i = 0; i < 8; ++i) {
                unsigned short h = f2bf(xf[8 + i]);
                vh1[i] = (short)h; vl1[i] = (short)f2bf(xf[8 + i] - bf2f(h));
            }
            *reinterpret_cast<short8*>(&xs_hi[xrow][xc])     = vh0;
            *reinterpret_cast<short8*>(&xs_hi[xrow][xc + 8]) = vh1;
            *reinterpret_cast<short8*>(&xs_lo[xrow][xc])     = vl0;
            *reinterpret_cast<short8*>(&xs_lo[xrow][xc + 8]) = vl1;
            *reinterpret_cast<short8*>(&ws_hi[wcol][wko])      = pwh0;
            *reinterpret_cast<short8*>(&ws_lo[wcol][wko])      = pwl0;
            *reinterpret_cast<short8*>(&ws_hi[wcol + 64][wko]) = pwh1;
            *reinterpret_cast<short8*>(&ws_lo[wcol + 64][wko]) = pwl1;
        }
        __syncthreads();
        if (k0 + 32 < CIN) { loadX(k0 + 32); loadW(k0 + 32); }   // issue next tile early
        int r = lane & 15, ko = (lane >> 4) * 8;
        short8 a_hi[2], a_lo[2];
        #pragma unroll
        for (int rt = 0; rt < 2; ++rt) {
            a_hi[rt] = *reinterpret_cast<const short8*>(&xs_hi[wid * 32 + rt * 16 + r][ko]);
            a_lo[rt] = *reinterpret_cast<const short8*>(&xs_lo[wid * 32 + rt * 16 + r][ko]);
        }
        #pragma unroll
        for (int ct = 0; ct < 8; ++ct) {
            short8 b_hi = *reinterpret_cast<const short8*>(&ws_hi[ct * 16 + r][ko]);
            short8 b_lo = *reinterpret_cast<const short8*>(&ws_lo[ct * 16 + r][ko]);
            #pragma unroll
            for (int rt = 0; rt < 2; ++rt) {
                acc[rt][ct] = __builtin_amdgcn_mfma_f32_16x16x32_bf16(a_hi[rt], b_hi, acc[rt][ct], 0, 0, 0);
                acc[rt][ct] = __builtin_amdgcn_mfma_f32_16x16x32_bf16(a_hi[rt], b_lo, acc[rt][ct], 0, 0, 0);
                acc[rt][ct] = __builtin_amdgcn_mfma_f32_16x16x32_bf16(a_lo[rt], b_hi, acc[rt][ct], 0, 0, 0);
            }
        }
        __syncthreads();
    }
    // epilogue: D row=(lane>>4)*4+j, col=lane&15 per 16x16 tile
    int cl = lane & 15, rg = lane >> 4;
    #pragma unroll
    for (int rt = 0; rt < 2; ++rt) {
        #pragma unroll
        for (int j = 0; j < 4; ++j) {
            int row = row0 + wid * 32 + rt * 16 + rg * 4 + j;
            if (row < NN) {
                unsigned short* hp = Hb + (size_t)row * CH + cl;
                #pragma unroll
                for (int ct = 0; ct < 8; ++ct)
                    hp[ct * 16] = f2bf(acc[rt][ct][j]);
            }
        }
    }
}

// ---------------- bucket totals -> exclusive scan ----------------

__global__ __launch_bounds__(256) void bucket_scan(const int* __restrict__ bucket_cursor,
                                                   int* __restrict__ bucket_start) {
    __shared__ int tmp[256];
    int t = threadIdx.x;
    int v = (t < NB) ? (bucket_cursor[t] - t * BUCKET_CAP) : 0;
    tmp[t] = v;
    __syncthreads();
    for (int off = 1; off < 256; off <<= 1) {
        int add = (t >= off) ? tmp[t - off] : 0;
        __syncthreads();
        tmp[t] += add;
        __syncthreads();
    }
    if (t < NB) bucket_start[t] = tmp[t] - v;
    if (t == NB - 1) bucket_start[NB] = tmp[t];   // == NE
}

// ---------------- in-bucket count + sort -> CSR, row_start, dinv ----------------

__global__ __launch_bounds__(1024) void bucket_sort(const unsigned int* __restrict__ pairs,
                                                    const int* __restrict__ bucket_cursor,
                                                    const int* __restrict__ bucket_start,
                                                    int* __restrict__ row_start,
                                                    float* __restrict__ dinv,
                                                    unsigned short* __restrict__ csr_src) {
    __shared__ int cnt[256];
    __shared__ int pref[256];
    __shared__ int cur[256];
    int b = blockIdx.x, t = threadIdx.x;
    int p0 = b * BUCKET_CAP;
    int ne = bucket_cursor[b] - p0;
    int out0 = bucket_start[b];
    if (t < 256) cnt[t] = 0;
    __syncthreads();
    for (int i = t; i < ne; i += 1024)
        atomicAdd(&cnt[(pairs[p0 + i] >> 16) & 255], 1);
    __syncthreads();
    if (t < 256) pref[t] = cnt[t];
    __syncthreads();
    for (int off = 1; off < 256; off <<= 1) {
        int add = (t < 256 && t >= off) ? pref[t - off] : 0;
        __syncthreads();
        if (t < 256) pref[t] += add;
        __syncthreads();
    }
    if (t < 256) {
        int n = (b << 8) + t;
        if (n < NN) {
            int rs = out0 + pref[t] - cnt[t];
            row_start[n] = rs;
            cur[t] = rs;
            dinv[n] = rsqrtf((float)(cnt[t] + 1));  // + self-loop
        }
    }
    if (b == NB - 1 && t == 0) row_start[NN] = NE;
    __syncthreads();
    for (int i = t; i < ne; i += 1024) {
        unsigned int p = pairs[p0 + i];
        int pos = atomicAdd(&cur[(p >> 16) & 255], 1);
        csr_src[pos] = (unsigned short)(p & 0xFFFF);
    }
}

// ---------------- agg1 + fused GEMV: h2 = relu(agg(h1)+b1) @ W2 ----------------
// (64,1): full VGPR budget so the 8 gathers stay in flight (r13's 28-VGPR
// schedule serialized them). GEMV: lane l owns out ch l; W2 (32KB) L1-resident.

__global__ __launch_bounds__(64, 1) void agg1_gemv_kernel(const unsigned int* __restrict__ H,   // bf16x2, ld=64
                                                          const int* __restrict__ row_start,
                                                          const unsigned short* __restrict__ csr_src,
                                                          const float* __restrict__ dinv,
                                                          const float* __restrict__ bias,
                                                          const float* __restrict__ W2,       // [128][64] fp32
                                                          unsigned short* __restrict__ H2b) { // bf16, ld=64
    int n = blockIdx.x;
    int l = threadIdx.x;                // lane = channel pair {2l, 2l+1}
    float dn = dinv[n];
    unsigned int us = H[n * 64 + l];
    float a0 = dn * bflo(us), a1 = dn * bfhi(us);   // self-loop
    float b0 = 0.f, b1 = 0.f, c0 = 0.f, c1 = 0.f, d0 = 0.f, d1 = 0.f;
    float e0a = 0.f, e1a = 0.f, f0 = 0.f, f1 = 0.f, g0 = 0.f, g1v = 0.f, h0 = 0.f, h1 = 0.f;
    int e0 = row_start[n], e1 = row_start[n + 1];
    for (int base = e0; base < e1; base += 64) {
        int m = min(64, e1 - base);
        int sv = csr_src[base + min(l, m - 1)];
        float wv = (l < m) ? dinv[sv] : 0.f;
        int j = 0;
        for (; j + 8 <= m; j += 8) {    // 8 independent row-gathers in flight
            int s0 = __shfl(sv, j),     s1 = __shfl(sv, j + 1);
            int s2 = __shfl(sv, j + 2), s3 = __shfl(sv, j + 3);
            int s4 = __shfl(sv, j + 4), s5 = __shfl(sv, j + 5);
            int s6 = __shfl(sv, j + 6), s7 = __shfl(sv, j + 7);
            float w0 = __shfl(wv, j),     w1 = __shfl(wv, j + 1);
            float w2 = __shfl(wv, j + 2), w3 = __shfl(wv, j + 3);
            float w4 = __shfl(wv, j + 4), w5 = __shfl(wv, j + 5);
            float w6 = __shfl(wv, j + 6), w7 = __shfl(wv, j + 7);
            unsigned int u0 = H[s0 * 64 + l];
            unsigned int u1 = H[s1 * 64 + l];
            unsigned int u2 = H[s2 * 64 + l];
            unsigned int u3 = H[s3 * 64 + l];
            unsigned int u4 = H[s4 * 64 + l];
            unsigned int u5 = H[s5 * 64 + l];
            unsigned int u6 = H[s6 * 64 + l];
            unsigned int u7 = H[s7 * 64 + l];
            a0  = fmaf(w0, bflo(u0), a0);  a1  = fmaf(w0, bfhi(u0), a1);
            b0  = fmaf(w1, bflo(u1), b0);  b1  = fmaf(w1, bfhi(u1), b1);
            c0  = fmaf(w2, bflo(u2), c0);  c1  = fmaf(w2, bfhi(u2), c1);
            d0  = fmaf(w3, bflo(u3), d0);  d1  = fmaf(w3, bfhi(u3), d1);
            e0a = fmaf(w4, bflo(u4), e0a); e1a = fmaf(w4, bfhi(u4), e1a);
            f0  = fmaf(w5, bflo(u5), f0);  f1  = fmaf(w5, bfhi(u5), f1);
            g0  = fmaf(w6, bflo(u6), g0);  g1v = fmaf(w6, bfhi(u6), g1v);
            h0  = fmaf(w7, bflo(u7), h0);  h1  = fmaf(w7, bfhi(u7), h1);
        }
        for (; j < m; ++j) {
            int s0 = __shfl(sv, j);
            float w0 = __shfl(wv, j);
            unsigned int u0 = H[s0 * 64 + l];
            a0 = fmaf(w0, bflo(u0), a0); a1 = fmaf(w0, bfhi(u0), a1);
        }
    }
    float s0 = ((a0 + b0) + (c0 + d0)) + ((e0a + f0) + (g0 + h0));
    float s1 = ((a1 + b1) + (c1 + d1)) + ((e1a + f1) + (g1v + h1));
    float2 bv = reinterpret_cast<const float2*>(bias)[l];
    float o0 = fmaxf(fmaf(dn, s0, bv.x), 0.f);   // g[2l]   (bias + ReLU)
    float o1 = fmaxf(fmaf(dn, s1, bv.y), 0.f);   // g[2l+1]

    // ---- fused GEMV: h2[l] = sum_k g[k] * W2[k][l], fp32, W2 L1-resident ----
    float hA = 0.f, hB = 0.f;
    #pragma unroll 4
    for (int sl = 0; sl < 64; sl += 2) {
        float ga0 = __shfl(o0, sl),     ga1 = __shfl(o1, sl);
        float gb0 = __shfl(o0, sl + 1), gb1 = __shfl(o1, sl + 1);
        hA = fmaf(ga0, W2[(2 * sl) * 64 + l],     fmaf(ga1, W2[(2 * sl + 1) * 64 + l], hA));
        hB = fmaf(gb0, W2[(2 * sl + 2) * 64 + l], fmaf(gb1, W2[(2 * sl + 3) * 64 + l], hB));
    }
    H2b[(size_t)n * 64 + l] = f2bf(hA + hB);
}

// ---------------- agg2 (bf16 gather, 8 edges in flight), + b2, no ReLU ----------------

__global__ __launch_bounds__(64, 1) void agg2_kernel(const unsigned int* __restrict__ H,   // bf16x2, ld=32
                                                     const int* __restrict__ row_start,
                                                     const unsigned short* __restrict__ csr_src,
                                                     const float* __restrict__ dinv,
                                                     const float* __restrict__ bias,
                                                     float* __restrict__ OUT) {
    int n = blockIdx.x;
    int l = threadIdx.x;
    int half = l >> 5;                  // lanes 0-31: even edges, 32-63: odd edges
    int c = l & 31;                     // channel pair {2c, 2c+1}
    float dn = dinv[n];
    unsigned int us = H[n * 32 + c];
    float a0 = half ? 0.f : dn * bflo(us);
    float a1 = half ? 0.f : dn * bfhi(us);
    float b0 = 0.f, b1 = 0.f, c0 = 0.f, c1 = 0.f, d0 = 0.f, d1 = 0.f;
    int e0 = row_start[n], e1 = row_start[n + 1];
    for (int base = e0; base < e1; base += 64) {
        int m = min(64, e1 - base);
        int sv = csr_src[base + min(l, m - 1)];
        float wv = (l < m) ? dinv[sv] : 0.f;
        int j = 0;
        for (; j + 8 <= m; j += 8) {    // per half-wave: 4 edges in flight (8 total)
            int jj0 = j + half, jj1 = j + 2 + half, jj2 = j + 4 + half, jj3 = j + 6 + half;
            int s0 = __shfl(sv, jj0), s1 = __shfl(sv, jj1);
            int s2 = __shfl(sv, jj2), s3 = __shfl(sv, jj3);
            float w0 = __shfl(wv, jj0), w1 = __shfl(wv, jj1);
            float w2 = __shfl(wv, jj2), w3 = __shfl(wv, jj3);
            unsigned int u0 = H[s0 * 32 + c];
            unsigned int u1 = H[s1 * 32 + c];
            unsigned int u2 = H[s2 * 32 + c];
            unsigned int u3 = H[s3 * 32 + c];
            a0 = fmaf(w0, bflo(u0), a0); a1 = fmaf(w0, bfhi(u0), a1);
            b0 = fmaf(w1, bflo(u1), b0); b1 = fmaf(w1, bfhi(u1), b1);
            c0 = fmaf(w2, bflo(u2), c0); c1 = fmaf(w2, bfhi(u2), c1);
            d0 = fmaf(w3, bflo(u3), d0); d1 = fmaf(w3, bfhi(u3), d1);
        }
        for (; j < m; j += 2) {
            int jj = j + half;
            int s = __shfl(sv, min(jj, m - 1));
            float w = __shfl(wv, jj);   // 0 when jj >= m (odd m, half=1)
            unsigned int u = H[s * 32 + c];
            a0 = fmaf(w, bflo(u), a0);
            a1 = fmaf(w, bfhi(u), a1);
        }
    }
    a0 = (a0 + b0) + (c0 + d0);
    a1 = (a1 + b1) + (c1 + d1);
    a0 += __shfl_xor(a0, 32);
    a1 += __shfl_xor(a1, 32);
    if (l < 32) {
        float2 bv = reinterpret_cast<const float2*>(bias)[c];
        float o0 = fmaf(dn, a0, bv.x);
        float o1 = fmaf(dn, a1, bv.y);
        reinterpret_cast<float2*>(OUT)[n * 32 + c] = make_float2(o0, o1);   // no ReLU
    }
}

// ---------------- launch ----------------

extern "C" void kernel_launch(void* const* d_in, const int* in_sizes, int n_in,
                              void* d_out, int out_size, void* d_ws, size_t ws_size,
                              hipStream_t stream) {
    const float* x  = (const float*)d_in[0];
    const int*   ei = (const int*)d_in[1];
    const float* W1 = (const float*)d_in[2];
    const float* b1 = (const float*)d_in[3];
    const float* W2 = (const float*)d_in[4];
    const float* b2 = (const float*)d_in[5];
    const int* srcI = ei;
    const int* dstI = ei + NE;
    float* out = (float*)d_out;

    char* ws = (char*)d_ws;
    size_t off = 0;
    auto take = [&](size_t bytes) {
        char* p = ws + off;
        off = (off + bytes + 255) & ~(size_t)255;
        return p;
    };
    int*            row_start     = (int*)take((size_t)(NN + 1) * 4);
    int*            bucket_cursor = (int*)take((size_t)NB * 4);
    int*            bucket_start  = (int*)take((size_t)(NB + 1) * 4);
    float*          dinv          = (float*)take((size_t)NN * 4);
    unsigned short* W1t_hi        = (unsigned short*)take((size_t)CH * CIN * 2);
    unsigned short* W1t_lo        = (unsigned short*)take((size_t)CH * CIN * 2);
    unsigned short* csr_src       = (unsigned short*)take((size_t)NE * 2);
    unsigned short* h1b           = (unsigned short*)take((size_t)NN * CH * 2);   // bf16
    unsigned short* h2b           = (unsigned short*)take((size_t)NN * CO * 2);   // bf16
    unsigned int*   pairs         = (unsigned int*)take((size_t)NB * BUCKET_CAP * 4); // 12.85 MB

    wprep<<<(CIN * CH + 255) / 256, 256, 0, stream>>>(W1, W1t_hi, W1t_lo, bucket_cursor);
    fused_gemm1_scatter<<<SCAT_BLOCKS + G1_TILES, 256, 0, stream>>>(srcI, dstI, bucket_cursor,
                                                                    pairs, x, W1t_hi, W1t_lo, h1b);
    bucket_scan<<<1, 256, 0, stream>>>(bucket_cursor, bucket_start);
    bucket_sort<<<NB, 1024, 0, stream>>>(pairs, bucket_cursor, bucket_start,
                                         row_start, dinv, csr_src);

    agg1_gemv_kernel<<<NN, 64, 0, stream>>>((const unsigned int*)h1b, row_start, csr_src,
                                            dinv, b1, W2, h2b);
    agg2_kernel<<<NN, 64, 0, stream>>>((const unsigned int*)h2b, row_start, csr_src, dinv, b2, out);
}

// Round 16
// 151.443 us; speedup vs baseline: 1.3059x; 1.3059x over previous
//
#include <hip/hip_runtime.h>

constexpr int NN  = 50000;
constexpr int NE  = 1600000;
constexpr int CIN = 384;
constexpr int CH  = 128;
constexpr int CO  = 64;

constexpr int NB = (NN + 255) / 256;              // 196 dst-buckets of 256 nodes
constexpr int BUCKET_CAP = 16384;                 // append region per bucket (mean 8163)
constexpr int SCAT_EPB     = 4096;                // 256 thr * 16 edges
constexpr int SCAT_BLOCKS  = (NE + SCAT_EPB - 1) / SCAT_EPB;     // 391
constexpr int G1_TILES     = (NN + 127) / 128;    // 391 blocks of 128 rows
constexpr int G2_TILES     = (NN + 127) / 128;    // 391

typedef __attribute__((ext_vector_type(8))) short short8;
typedef __attribute__((ext_vector_type(4))) float f32x4;

// ---------------- bf16 helpers ----------------

__device__ inline unsigned short f2bf(float f) {
    union { float f; unsigned int u; } v; v.f = f;
    unsigned int u = v.u + 0x7FFFu + ((v.u >> 16) & 1u);   // round-to-nearest-even
    return (unsigned short)(u >> 16);
}
__device__ inline float bf2f(unsigned short h) { return __uint_as_float((unsigned int)h << 16); }
__device__ inline float bflo(unsigned int u) { return __uint_as_float(u << 16); }
__device__ inline float bfhi(unsigned int u) { return __uint_as_float(u & 0xFFFF0000u); }

// ---------------- W transpose + hi/lo bf16 split + cursor init ----------------

__global__ __launch_bounds__(256) void wprep(const float* __restrict__ W1, const float* __restrict__ W2,
                                             unsigned short* __restrict__ W1t_hi, unsigned short* __restrict__ W1t_lo,
                                             unsigned short* __restrict__ W2t_hi, unsigned short* __restrict__ W2t_lo,
                                             int* __restrict__ bucket_cursor) {
    int i = blockIdx.x * 256 + threadIdx.x;
    if (blockIdx.x == 0 && threadIdx.x < NB)
        bucket_cursor[threadIdx.x] = threadIdx.x * BUCKET_CAP;
    if (i < CIN * CH) {
        int k = i / CH, c = i % CH;
        float v = W1[i];
        unsigned short h = f2bf(v);
        W1t_hi[c * CIN + k] = h;
        W1t_lo[c * CIN + k] = f2bf(v - bf2f(h));
    } else if (i < CIN * CH + CH * CO) {
        int j = i - CIN * CH;
        int k = j / CO, c = j % CO;
        float v = W2[j];
        unsigned short h = f2bf(v);
        W2t_hi[c * CH + k] = h;
        W2t_lo[c * CH + k] = f2bf(v - bf2f(h));
    }
}

// ---------------- fused MFMA-GEMM1 + bucketed edge scatter (sequential roles) ----------------

__global__ __launch_bounds__(256) void fused_gemm1_scatter(const int* __restrict__ src,
                                                           const int* __restrict__ dst,
                                                           int* __restrict__ bucket_cursor,
                                                           unsigned int* __restrict__ pairs,
                                                           const float* __restrict__ X,
                                                           const unsigned short* __restrict__ Wt_hi,
                                                           const unsigned short* __restrict__ Wt_lo,
                                                           unsigned short* __restrict__ Hb) {
    __shared__ unsigned short xs_hi[128][40];   // [row][k], stride 40 -> 2-way bank alias (free)
    __shared__ unsigned short xs_lo[128][40];
    __shared__ unsigned short ws_hi[128][40];   // [col][k]
    __shared__ unsigned short ws_lo[128][40];
    __shared__ int hist[NB];
    __shared__ int base_s[NB];

    int tid = threadIdx.x;
    if (blockIdx.x < SCAT_BLOCKS) {
        int e0 = blockIdx.x * SCAT_EPB;
        for (int i = tid; i < NB; i += 256) hist[i] = 0;
        __syncthreads();
        int key[16];
        unsigned int pay[16];
        #pragma unroll
        for (int k = 0; k < 16; ++k) {
            int e = e0 + k * 256 + tid;
            if (e < NE) {
                int s = src[e], d = dst[e];
                int b = d >> 8;
                int pos = atomicAdd(&hist[b], 1);
                key[k] = b | (pos << 8);
                pay[k] = (unsigned int)s | ((unsigned int)(d & 255) << 16);
            } else {
                key[k] = -1;
            }
        }
        __syncthreads();
        for (int i = tid; i < NB; i += 256)
            base_s[i] = hist[i] ? atomicAdd(&bucket_cursor[i], hist[i]) : 0;
        __syncthreads();
        #pragma unroll
        for (int k = 0; k < 16; ++k) {
            if (key[k] >= 0) {
                int b = key[k] & 255, pos = key[k] >> 8;
                pairs[base_s[b] + pos] = pay[k];
            }
        }
        return;
    }

    // ---- GEMM1: 128 rows x 128 cols per block, 4 waves x (32r x 128c) ----
    int wid = tid >> 6, lane = tid & 63;
    int row0 = (blockIdx.x - SCAT_BLOCKS) * 128;
    f32x4 acc[2][8] = {};

    int xrow = tid >> 1, xc = (tid & 1) * 16;
    int grow = row0 + xrow;
    int wcol = tid >> 2, wko = (tid & 3) * 8;

    float xf[16];
    short8 pwh0, pwl0, pwh1, pwl1;

    auto loadX = [&](int k0) {
        if (grow < NN) {
            const float4* p = reinterpret_cast<const float4*>(X + (size_t)grow * CIN + k0 + xc);
            float4 v0 = p[0], v1 = p[1], v2 = p[2], v3 = p[3];
            xf[0]=v0.x; xf[1]=v0.y; xf[2]=v0.z; xf[3]=v0.w;
            xf[4]=v1.x; xf[5]=v1.y; xf[6]=v1.z; xf[7]=v1.w;
            xf[8]=v2.x; xf[9]=v2.y; xf[10]=v2.z; xf[11]=v2.w;
            xf[12]=v3.x; xf[13]=v3.y; xf[14]=v3.z; xf[15]=v3.w;
        } else {
            #pragma unroll
            for (int i = 0; i < 16; ++i) xf[i] = 0.f;
        }
    };
    auto loadW = [&](int k0) {
        pwh0 = *reinterpret_cast<const short8*>(Wt_hi + (size_t)wcol * CIN + k0 + wko);
        pwl0 = *reinterpret_cast<const short8*>(Wt_lo + (size_t)wcol * CIN + k0 + wko);
        pwh1 = *reinterpret_cast<const short8*>(Wt_hi + (size_t)(wcol + 64) * CIN + k0 + wko);
        pwl1 = *reinterpret_cast<const short8*>(Wt_lo + (size_t)(wcol + 64) * CIN + k0 + wko);
    };

    loadX(0); loadW(0);
    for (int k0 = 0; k0 < CIN; k0 += 32) {
        // convert + LDS write from prefetched regs
        {
            short8 vh0, vh1, vl0, vl1;
            #pragma unroll
            for (int i = 0; i < 8; ++i) {
                unsigned short h = f2bf(xf[i]);
                vh0[i] = (short)h; vl0[i] = (short)f2bf(xf[i] - bf2f(h));
            }
            #pragma unroll
            for (int i = 0; i < 8; ++i) {
                unsigned short h = f2bf(xf[8 + i]);
                vh1[i] = (short)h; vl1[i] = (short)f2bf(xf[8 + i] - bf2f(h));
            }
            *reinterpret_cast<short8*>(&xs_hi[xrow][xc])     = vh0;
            *reinterpret_cast<short8*>(&xs_hi[xrow][xc + 8]) = vh1;
            *reinterpret_cast<short8*>(&xs_lo[xrow][xc])     = vl0;
            *reinterpret_cast<short8*>(&xs_lo[xrow][xc + 8]) = vl1;
            *reinterpret_cast<short8*>(&ws_hi[wcol][wko])      = pwh0;
            *reinterpret_cast<short8*>(&ws_lo[wcol][wko])      = pwl0;
            *reinterpret_cast<short8*>(&ws_hi[wcol + 64][wko]) = pwh1;
            *reinterpret_cast<short8*>(&ws_lo[wcol + 64][wko]) = pwl1;
        }
        __syncthreads();
        if (k0 + 32 < CIN) { loadX(k0 + 32); loadW(k0 + 32); }   // issue next tile early
        int r = lane & 15, ko = (lane >> 4) * 8;
        short8 a_hi[2], a_lo[2];
        #pragma unroll
        for (int rt = 0; rt < 2; ++rt) {
            a_hi[rt] = *reinterpret_cast<const short8*>(&xs_hi[wid * 32 + rt * 16 + r][ko]);
            a_lo[rt] = *reinterpret_cast<const short8*>(&xs_lo[wid * 32 + rt * 16 + r][ko]);
        }
        #pragma unroll
        for (int ct = 0; ct < 8; ++ct) {
            short8 b_hi = *reinterpret_cast<const short8*>(&ws_hi[ct * 16 + r][ko]);
            short8 b_lo = *reinterpret_cast<const short8*>(&ws_lo[ct * 16 + r][ko]);
            #pragma unroll
            for (int rt = 0; rt < 2; ++rt) {
                acc[rt][ct] = __builtin_amdgcn_mfma_f32_16x16x32_bf16(a_hi[rt], b_hi, acc[rt][ct], 0, 0, 0);
                acc[rt][ct] = __builtin_amdgcn_mfma_f32_16x16x32_bf16(a_hi[rt], b_lo, acc[rt][ct], 0, 0, 0);
                acc[rt][ct] = __builtin_amdgcn_mfma_f32_16x16x32_bf16(a_lo[rt], b_hi, acc[rt][ct], 0, 0, 0);
            }
        }
        __syncthreads();
    }
    // epilogue: D row=(lane>>4)*4+j, col=lane&15 per 16x16 tile
    int cl = lane & 15, rg = lane >> 4;
    #pragma unroll
    for (int rt = 0; rt < 2; ++rt) {
        #pragma unroll
        for (int j = 0; j < 4; ++j) {
            int row = row0 + wid * 32 + rt * 16 + rg * 4 + j;
            if (row < NN) {
                unsigned short* hp = Hb + (size_t)row * CH + cl;
                #pragma unroll
                for (int ct = 0; ct < 8; ++ct)
                    hp[ct * 16] = f2bf(acc[rt][ct][j]);
            }
        }
    }
}

// ---------------- in-bucket count + sort -> CSR, row_start, dinv ----------------
// bucket_scan merged in: each block computes its own exclusive bucket prefix
// from the 196 cursor totals (in-LDS scan) -- one fewer serial launch.

__global__ __launch_bounds__(1024) void bucket_sort(const unsigned int* __restrict__ pairs,
                                                    const int* __restrict__ bucket_cursor,
                                                    int* __restrict__ row_start,
                                                    float* __restrict__ dinv,
                                                    unsigned short* __restrict__ csr_src) {
    __shared__ int bpre[256];
    __shared__ int cnt[256];
    __shared__ int pref[256];
    __shared__ int cur[256];
    int b = blockIdx.x, t = threadIdx.x;
    int p0 = b * BUCKET_CAP;
    int ne = bucket_cursor[b] - p0;

    // exclusive prefix over bucket totals -> out0 for this bucket
    if (t < 256) {
        int v = (t < NB) ? (bucket_cursor[t] - t * BUCKET_CAP) : 0;
        bpre[t] = v;
    }
    __syncthreads();
    for (int off = 1; off < 256; off <<= 1) {
        int add = (t < 256 && t >= off) ? bpre[t - off] : 0;
        __syncthreads();
        if (t < 256) bpre[t] += add;
        __syncthreads();
    }
    int out0 = (b == 0) ? 0 : bpre[b - 1];

    if (t < 256) cnt[t] = 0;
    __syncthreads();
    for (int i = t; i < ne; i += 1024)
        atomicAdd(&cnt[(pairs[p0 + i] >> 16) & 255], 1);
    __syncthreads();
    if (t < 256) pref[t] = cnt[t];
    __syncthreads();
    for (int off = 1; off < 256; off <<= 1) {
        int add = (t < 256 && t >= off) ? pref[t - off] : 0;
        __syncthreads();
        if (t < 256) pref[t] += add;
        __syncthreads();
    }
    if (t < 256) {
        int n = (b << 8) + t;
        if (n < NN) {
            int rs = out0 + pref[t] - cnt[t];
            row_start[n] = rs;
            cur[t] = rs;
            dinv[n] = rsqrtf((float)(cnt[t] + 1));  // + self-loop
        }
    }
    if (b == NB - 1 && t == 0) row_start[NN] = NE;
    __syncthreads();
    for (int i = t; i < ne; i += 1024) {
        unsigned int p = pairs[p0 + i];
        int pos = atomicAdd(&cur[(p >> 16) & 255], 1);
        csr_src[pos] = (unsigned short)(p & 0xFFFF);
    }
}

// ---------------- MFMA GEMM2 (r7 structure): h2 = g1 @ W2, bf16 out ----------------

__global__ __launch_bounds__(256) void gemm2_kernel(const float* __restrict__ X,
                                                    const unsigned short* __restrict__ Wt_hi,
                                                    const unsigned short* __restrict__ Wt_lo,
                                                    unsigned short* __restrict__ Hb) {
    __shared__ unsigned short xs_hi[128][40];
    __shared__ unsigned short xs_lo[128][40];
    __shared__ unsigned short ws_hi[64][40];
    __shared__ unsigned short ws_lo[64][40];

    int tid = threadIdx.x;
    int wid = tid >> 6, lane = tid & 63;
    int row0 = blockIdx.x * 128;
    f32x4 acc[2][4] = {};

    for (int k0 = 0; k0 < CH; k0 += 32) {
        {
            int row = tid >> 1, c = (tid & 1) * 16;
            int grow = row0 + row;
            float f[16];
            if (grow < NN) {
                const float4* p = reinterpret_cast<const float4*>(X + (size_t)grow * CH + k0 + c);
                float4 v0 = p[0], v1 = p[1], v2 = p[2], v3 = p[3];
                f[0]=v0.x; f[1]=v0.y; f[2]=v0.z; f[3]=v0.w;
                f[4]=v1.x; f[5]=v1.y; f[6]=v1.z; f[7]=v1.w;
                f[8]=v2.x; f[9]=v2.y; f[10]=v2.z; f[11]=v2.w;
                f[12]=v3.x; f[13]=v3.y; f[14]=v3.z; f[15]=v3.w;
            } else {
                #pragma unroll
                for (int i = 0; i < 16; ++i) f[i] = 0.f;
            }
            short8 vh0, vh1, vl0, vl1;
            #pragma unroll
            for (int i = 0; i < 8; ++i) {
                unsigned short h = f2bf(f[i]);
                vh0[i] = (short)h; vl0[i] = (short)f2bf(f[i] - bf2f(h));
            }
            #pragma unroll
            for (int i = 0; i < 8; ++i) {
                unsigned short h = f2bf(f[8 + i]);
                vh1[i] = (short)h; vl1[i] = (short)f2bf(f[8 + i] - bf2f(h));
            }
            *reinterpret_cast<short8*>(&xs_hi[row][c])     = vh0;
            *reinterpret_cast<short8*>(&xs_hi[row][c + 8]) = vh1;
            *reinterpret_cast<short8*>(&xs_lo[row][c])     = vl0;
            *reinterpret_cast<short8*>(&xs_lo[row][c + 8]) = vl1;
        }
        if (tid < 256) {   // 64 cols x 4 chunks = 256 chunks, 1 per thread
            int col = tid >> 2, ko = (tid & 3) * 8;
            *reinterpret_cast<short8*>(&ws_hi[col][ko]) =
                *reinterpret_cast<const short8*>(Wt_hi + (size_t)col * CH + k0 + ko);
            *reinterpret_cast<short8*>(&ws_lo[col][ko]) =
                *reinterpret_cast<const short8*>(Wt_lo + (size_t)col * CH + k0 + ko);
        }
        __syncthreads();
        int r = lane & 15, ko = (lane >> 4) * 8;
        short8 a_hi[2], a_lo[2];
        #pragma unroll
        for (int rt = 0; rt < 2; ++rt) {
            a_hi[rt] = *reinterpret_cast<const short8*>(&xs_hi[wid * 32 + rt * 16 + r][ko]);
            a_lo[rt] = *reinterpret_cast<const short8*>(&xs_lo[wid * 32 + rt * 16 + r][ko]);
        }
        #pragma unroll
        for (int ct = 0; ct < 4; ++ct) {
            short8 b_hi = *reinterpret_cast<const short8*>(&ws_hi[ct * 16 + r][ko]);
            short8 b_lo = *reinterpret_cast<const short8*>(&ws_lo[ct * 16 + r][ko]);
            #pragma unroll
            for (int rt = 0; rt < 2; ++rt) {
                acc[rt][ct] = __builtin_amdgcn_mfma_f32_16x16x32_bf16(a_hi[rt], b_hi, acc[rt][ct], 0, 0, 0);
                acc[rt][ct] = __builtin_amdgcn_mfma_f32_16x16x32_bf16(a_hi[rt], b_lo, acc[rt][ct], 0, 0, 0);
                acc[rt][ct] = __builtin_amdgcn_mfma_f32_16x16x32_bf16(a_lo[rt], b_hi, acc[rt][ct], 0, 0, 0);
            }
        }
        __syncthreads();
    }
    int cl = lane & 15, rg = lane >> 4;
    #pragma unroll
    for (int rt = 0; rt < 2; ++rt) {
        #pragma unroll
        for (int j = 0; j < 4; ++j) {
            int row = row0 + wid * 32 + rt * 16 + rg * 4 + j;
            if (row < NN) {
                unsigned short* hp = Hb + (size_t)row * CO + cl;
                #pragma unroll
                for (int ct = 0; ct < 4; ++ct)
                    hp[ct * 16] = f2bf(acc[rt][ct][j]);
            }
        }
    }
}

// ---------------- CSR gather-aggregation (bf16, 1 wave/node, 8 edges in flight) ----------------

__global__ __launch_bounds__(64) void agg1_kernel(const unsigned int* __restrict__ H,   // bf16x2, ld=64
                                                  const int* __restrict__ row_start,
                                                  const unsigned short* __restrict__ csr_src,
                                                  const float* __restrict__ dinv,
                                                  const float* __restrict__ bias,
                                                  float* __restrict__ OUT) {
    int n = blockIdx.x;
    int l = threadIdx.x;                // lane = channel pair {2l, 2l+1}
    float dn = dinv[n];
    unsigned int us = H[n * 64 + l];
    float a0 = dn * bflo(us), a1 = dn * bfhi(us);   // self-loop
    float b0 = 0.f, b1 = 0.f, c0 = 0.f, c1 = 0.f, d0 = 0.f, d1 = 0.f;
    float e0a = 0.f, e1a = 0.f, f0 = 0.f, f1 = 0.f, g0 = 0.f, g1v = 0.f, h0 = 0.f, h1 = 0.f;
    int e0 = row_start[n], e1 = row_start[n + 1];
    for (int base = e0; base < e1; base += 64) {
        int m = min(64, e1 - base);
        int sv = csr_src[base + min(l, m - 1)];
        float wv = (l < m) ? dinv[sv] : 0.f;
        int j = 0;
        for (; j + 8 <= m; j += 8) {    // 8 independent row-gathers in flight
            int s0 = __shfl(sv, j),     s1 = __shfl(sv, j + 1);
            int s2 = __shfl(sv, j + 2), s3 = __shfl(sv, j + 3);
            int s4 = __shfl(sv, j + 4), s5 = __shfl(sv, j + 5);
            int s6 = __shfl(sv, j + 6), s7 = __shfl(sv, j + 7);
            float w0 = __shfl(wv, j),     w1 = __shfl(wv, j + 1);
            float w2 = __shfl(wv, j + 2), w3 = __shfl(wv, j + 3);
            float w4 = __shfl(wv, j + 4), w5 = __shfl(wv, j + 5);
            float w6 = __shfl(wv, j + 6), w7 = __shfl(wv, j + 7);
            unsigned int u0 = H[s0 * 64 + l];
            unsigned int u1 = H[s1 * 64 + l];
            unsigned int u2 = H[s2 * 64 + l];
            unsigned int u3 = H[s3 * 64 + l];
            unsigned int u4 = H[s4 * 64 + l];
            unsigned int u5 = H[s5 * 64 + l];
            unsigned int u6 = H[s6 * 64 + l];
            unsigned int u7 = H[s7 * 64 + l];
            a0  = fmaf(w0, bflo(u0), a0);  a1  = fmaf(w0, bfhi(u0), a1);
            b0  = fmaf(w1, bflo(u1), b0);  b1  = fmaf(w1, bfhi(u1), b1);
            c0  = fmaf(w2, bflo(u2), c0);  c1  = fmaf(w2, bfhi(u2), c1);
            d0  = fmaf(w3, bflo(u3), d0);  d1  = fmaf(w3, bfhi(u3), d1);
            e0a = fmaf(w4, bflo(u4), e0a); e1a = fmaf(w4, bfhi(u4), e1a);
            f0  = fmaf(w5, bflo(u5), f0);  f1  = fmaf(w5, bfhi(u5), f1);
            g0  = fmaf(w6, bflo(u6), g0);  g1v = fmaf(w6, bfhi(u6), g1v);
            h0  = fmaf(w7, bflo(u7), h0);  h1  = fmaf(w7, bfhi(u7), h1);
        }
        for (; j < m; ++j) {
            int s0 = __shfl(sv, j);
            float w0 = __shfl(wv, j);
            unsigned int u0 = H[s0 * 64 + l];
            a0 = fmaf(w0, bflo(u0), a0); a1 = fmaf(w0, bfhi(u0), a1);
        }
    }
    float s0 = ((a0 + b0) + (c0 + d0)) + ((e0a + f0) + (g0 + h0));
    float s1 = ((a1 + b1) + (c1 + d1)) + ((e1a + f1) + (g1v + h1));
    float2 bv = reinterpret_cast<const float2*>(bias)[l];
    float o0 = fmaf(dn, s0, bv.x);
    float o1 = fmaf(dn, s1, bv.y);
    reinterpret_cast<float2*>(OUT)[n * 64 + l] = make_float2(fmaxf(o0, 0.f), fmaxf(o1, 0.f));
}

__global__ __launch_bounds__(64) void agg2_kernel(const unsigned int* __restrict__ H,   // bf16x2, ld=32
                                                  const int* __restrict__ row_start,
                                                  const unsigned short* __restrict__ csr_src,
                                                  const float* __restrict__ dinv,
                                                  const float* __restrict__ bias,
                                                  float* __restrict__ OUT) {
    int n = blockIdx.x;
    int l = threadIdx.x;
    int half = l >> 5;                  // lanes 0-31: even edges, 32-63: odd edges
    int c = l & 31;                     // channel pair {2c, 2c+1}
    float dn = dinv[n];
    unsigned int us = H[n * 32 + c];
    float a0 = half ? 0.f : dn * bflo(us);
    float a1 = half ? 0.f : dn * bfhi(us);
    float b0 = 0.f, b1 = 0.f, c0 = 0.f, c1 = 0.f, d0 = 0.f, d1 = 0.f;
    int e0 = row_start[n], e1 = row_start[n + 1];
    for (int base = e0; base < e1; base += 64) {
        int m = min(64, e1 - base);
        int sv = csr_src[base + min(l, m - 1)];
        float wv = (l < m) ? dinv[sv] : 0.f;
        int j = 0;
        for (; j + 8 <= m; j += 8) {    // per half-wave: 4 edges in flight (8 total)
            int jj0 = j + half, jj1 = j + 2 + half, jj2 = j + 4 + half, jj3 = j + 6 + half;
            int s0 = __shfl(sv, jj0), s1 = __shfl(sv, jj1);
            int s2 = __shfl(sv, jj2), s3 = __shfl(sv, jj3);
            float w0 = __shfl(wv, jj0), w1 = __shfl(wv, jj1);
            float w2 = __shfl(wv, jj2), w3 = __shfl(wv, jj3);
            unsigned int u0 = H[s0 * 32 + c];
            unsigned int u1 = H[s1 * 32 + c];
            unsigned int u2 = H[s2 * 32 + c];
            unsigned int u3 = H[s3 * 32 + c];
            a0 = fmaf(w0, bflo(u0), a0); a1 = fmaf(w0, bfhi(u0), a1);
            b0 = fmaf(w1, bflo(u1), b0); b1 = fmaf(w1, bfhi(u1), b1);
            c0 = fmaf(w2, bflo(u2), c0); c1 = fmaf(w2, bfhi(u2), c1);
            d0 = fmaf(w3, bflo(u3), d0); d1 = fmaf(w3, bfhi(u3), d1);
        }
        for (; j < m; j += 2) {
            int jj = j + half;
            int s = __shfl(sv, min(jj, m - 1));
            float w = __shfl(wv, jj);   // 0 when jj >= m (odd m, half=1)
            unsigned int u = H[s * 32 + c];
            a0 = fmaf(w, bflo(u), a0);
            a1 = fmaf(w, bfhi(u), a1);
        }
    }
    a0 = (a0 + b0) + (c0 + d0);
    a1 = (a1 + b1) + (c1 + d1);
    a0 += __shfl_xor(a0, 32);
    a1 += __shfl_xor(a1, 32);
    if (l < 32) {
        float2 bv = reinterpret_cast<const float2*>(bias)[c];
        float o0 = fmaf(dn, a0, bv.x);
        float o1 = fmaf(dn, a1, bv.y);
        reinterpret_cast<float2*>(OUT)[n * 32 + c] = make_float2(o0, o1);   // no ReLU
    }
}

// ---------------- launch ----------------

extern "C" void kernel_launch(void* const* d_in, const int* in_sizes, int n_in,
                              void* d_out, int out_size, void* d_ws, size_t ws_size,
                              hipStream_t stream) {
    const float* x  = (const float*)d_in[0];
    const int*   ei = (const int*)d_in[1];
    const float* W1 = (const float*)d_in[2];
    const float* b1 = (const float*)d_in[3];
    const float* W2 = (const float*)d_in[4];
    const float* b2 = (const float*)d_in[5];
    const int* srcI = ei;
    const int* dstI = ei + NE;
    float* out = (float*)d_out;

    char* ws = (char*)d_ws;
    size_t off = 0;
    auto take = [&](size_t bytes) {
        char* p = ws + off;
        off = (off + bytes + 255) & ~(size_t)255;
        return p;
    };
    int*            row_start     = (int*)take((size_t)(NN + 1) * 4);
    int*            bucket_cursor = (int*)take((size_t)NB * 4);
    float*          dinv          = (float*)take((size_t)NN * 4);
    unsigned short* W1t_hi        = (unsigned short*)take((size_t)CH * CIN * 2);
    unsigned short* W1t_lo        = (unsigned short*)take((size_t)CH * CIN * 2);
    unsigned short* W2t_hi        = (unsigned short*)take((size_t)CO * CH * 2);
    unsigned short* W2t_lo        = (unsigned short*)take((size_t)CO * CH * 2);
    unsigned short* csr_src       = (unsigned short*)take((size_t)NE * 2);
    unsigned short* h1b           = (unsigned short*)take((size_t)NN * CH * 2);   // bf16
    float*          g1            = (float*)take((size_t)NN * CH * 4);            // fp32
    unsigned short* h2b           = (unsigned short*)take((size_t)NN * CO * 2);   // bf16
    // pairs aliases g1: pairs dead (after bucket_sort) before agg1 writes g1
    unsigned int*   pairs         = (unsigned int*)g1;   // NB*BUCKET_CAP*4 = 12.85 MB <= 25.6 MB

    wprep<<<(CIN * CH + CH * CO + 255) / 256, 256, 0, stream>>>(W1, W2, W1t_hi, W1t_lo,
                                                                W2t_hi, W2t_lo, bucket_cursor);
    fused_gemm1_scatter<<<SCAT_BLOCKS + G1_TILES, 256, 0, stream>>>(srcI, dstI, bucket_cursor,
                                                                    pairs, x, W1t_hi, W1t_lo, h1b);
    bucket_sort<<<NB, 1024, 0, stream>>>(pairs, bucket_cursor, row_start, dinv, csr_src);

    agg1_kernel<<<NN, 64, 0, stream>>>((const unsigned int*)h1b, row_start, csr_src, dinv, b1, g1);
    gemm2_kernel<<<G2_TILES, 256, 0, stream>>>(g1, W2t_hi, W2t_lo, h2b);
    agg2_kernel<<<NN, 64, 0, stream>>>((const unsigned int*)h2b, row_start, csr_src, dinv, b2, out);
}

// Round 17
// 147.973 us; speedup vs baseline: 1.3365x; 1.0235x over previous
//
#include <hip/hip_runtime.h>

constexpr int NN  = 50000;
constexpr int NE  = 1600000;
constexpr int CIN = 384;
constexpr int CH  = 128;
constexpr int CO  = 64;

constexpr int NB = (NN + 255) / 256;              // 196 dst-buckets of 256 nodes
constexpr int BUCKET_CAP = 16384;                 // append region per bucket (mean 8163)
constexpr int SCAT_EPB     = 4096;                // 256 thr * 16 edges
constexpr int SCAT_BLOCKS  = (NE + SCAT_EPB - 1) / SCAT_EPB;     // 391
constexpr int G1_TILES     = (NN + 127) / 128;    // 391 blocks of 128 rows
constexpr int G2_TILES     = (NN + 127) / 128;    // 391

typedef __attribute__((ext_vector_type(8))) short short8;
typedef __attribute__((ext_vector_type(4))) float f32x4;

// ---------------- bf16 helpers ----------------

__device__ inline unsigned short f2bf(float f) {
    union { float f; unsigned int u; } v; v.f = f;
    unsigned int u = v.u + 0x7FFFu + ((v.u >> 16) & 1u);   // round-to-nearest-even
    return (unsigned short)(u >> 16);
}
__device__ inline float bf2f(unsigned short h) { return __uint_as_float((unsigned int)h << 16); }
__device__ inline float bflo(unsigned int u) { return __uint_as_float(u << 16); }
__device__ inline float bfhi(unsigned int u) { return __uint_as_float(u & 0xFFFF0000u); }

// ---------------- W transpose + hi/lo bf16 split + cursor init ----------------

__global__ __launch_bounds__(256) void wprep(const float* __restrict__ W1, const float* __restrict__ W2,
                                             unsigned short* __restrict__ W1t_hi, unsigned short* __restrict__ W1t_lo,
                                             unsigned short* __restrict__ W2t_hi, unsigned short* __restrict__ W2t_lo,
                                             int* __restrict__ bucket_cursor) {
    int i = blockIdx.x * 256 + threadIdx.x;
    if (blockIdx.x == 0 && threadIdx.x < NB)
        bucket_cursor[threadIdx.x] = threadIdx.x * BUCKET_CAP;
    if (i < CIN * CH) {
        int k = i / CH, c = i % CH;
        float v = W1[i];
        unsigned short h = f2bf(v);
        W1t_hi[c * CIN + k] = h;
        W1t_lo[c * CIN + k] = f2bf(v - bf2f(h));
    } else if (i < CIN * CH + CH * CO) {
        int j = i - CIN * CH;
        int k = j / CO, c = j % CO;
        float v = W2[j];
        unsigned short h = f2bf(v);
        W2t_hi[c * CH + k] = h;
        W2t_lo[c * CH + k] = f2bf(v - bf2f(h));
    }
}

// ---------------- fused MFMA-GEMM1 + bucketed edge scatter (sequential roles) ----------------

__global__ __launch_bounds__(256) void fused_gemm1_scatter(const int* __restrict__ src,
                                                           const int* __restrict__ dst,
                                                           int* __restrict__ bucket_cursor,
                                                           unsigned int* __restrict__ pairs,
                                                           const float* __restrict__ X,
                                                           const unsigned short* __restrict__ Wt_hi,
                                                           const unsigned short* __restrict__ Wt_lo,
                                                           unsigned short* __restrict__ Hb) {
    __shared__ unsigned short xs_hi[128][40];   // [row][k], stride 40 -> 2-way bank alias (free)
    __shared__ unsigned short xs_lo[128][40];
    __shared__ unsigned short ws_hi[128][40];   // [col][k]
    __shared__ unsigned short ws_lo[128][40];
    __shared__ int hist[NB];
    __shared__ int base_s[NB];

    int tid = threadIdx.x;
    if (blockIdx.x < SCAT_BLOCKS) {
        int e0 = blockIdx.x * SCAT_EPB;
        for (int i = tid; i < NB; i += 256) hist[i] = 0;
        __syncthreads();
        int key[16];
        unsigned int pay[16];
        #pragma unroll
        for (int k = 0; k < 16; ++k) {
            int e = e0 + k * 256 + tid;
            if (e < NE) {
                int s = src[e], d = dst[e];
                int b = d >> 8;
                int pos = atomicAdd(&hist[b], 1);
                key[k] = b | (pos << 8);
                pay[k] = (unsigned int)s | ((unsigned int)(d & 255) << 16);
            } else {
                key[k] = -1;
            }
        }
        __syncthreads();
        for (int i = tid; i < NB; i += 256)
            base_s[i] = hist[i] ? atomicAdd(&bucket_cursor[i], hist[i]) : 0;
        __syncthreads();
        #pragma unroll
        for (int k = 0; k < 16; ++k) {
            if (key[k] >= 0) {
                int b = key[k] & 255, pos = key[k] >> 8;
                pairs[base_s[b] + pos] = pay[k];
            }
        }
        return;
    }

    // ---- GEMM1: 128 rows x 128 cols per block, 4 waves x (32r x 128c) ----
    int wid = tid >> 6, lane = tid & 63;
    int row0 = (blockIdx.x - SCAT_BLOCKS) * 128;
    f32x4 acc[2][8] = {};

    int xrow = tid >> 1, xc = (tid & 1) * 16;
    int grow = row0 + xrow;
    int wcol = tid >> 2, wko = (tid & 3) * 8;

    float xf[16];
    short8 pwh0, pwl0, pwh1, pwl1;

    auto loadX = [&](int k0) {
        if (grow < NN) {
            const float4* p = reinterpret_cast<const float4*>(X + (size_t)grow * CIN + k0 + xc);
            float4 v0 = p[0], v1 = p[1], v2 = p[2], v3 = p[3];
            xf[0]=v0.x; xf[1]=v0.y; xf[2]=v0.z; xf[3]=v0.w;
            xf[4]=v1.x; xf[5]=v1.y; xf[6]=v1.z; xf[7]=v1.w;
            xf[8]=v2.x; xf[9]=v2.y; xf[10]=v2.z; xf[11]=v2.w;
            xf[12]=v3.x; xf[13]=v3.y; xf[14]=v3.z; xf[15]=v3.w;
        } else {
            #pragma unroll
            for (int i = 0; i < 16; ++i) xf[i] = 0.f;
        }
    };
    auto loadW = [&](int k0) {
        pwh0 = *reinterpret_cast<const short8*>(Wt_hi + (size_t)wcol * CIN + k0 + wko);
        pwl0 = *reinterpret_cast<const short8*>(Wt_lo + (size_t)wcol * CIN + k0 + wko);
        pwh1 = *reinterpret_cast<const short8*>(Wt_hi + (size_t)(wcol + 64) * CIN + k0 + wko);
        pwl1 = *reinterpret_cast<const short8*>(Wt_lo + (size_t)(wcol + 64) * CIN + k0 + wko);
    };

    loadX(0); loadW(0);
    for (int k0 = 0; k0 < CIN; k0 += 32) {
        // convert + LDS write from prefetched regs
        {
            short8 vh0, vh1, vl0, vl1;
            #pragma unroll
            for (int i = 0; i < 8; ++i) {
                unsigned short h = f2bf(xf[i]);
                vh0[i] = (short)h; vl0[i] = (short)f2bf(xf[i] - bf2f(h));
            }
            #pragma unroll
            for (int i = 0; i < 8; ++i) {
                unsigned short h = f2bf(xf[8 + i]);
                vh1[i] = (short)h; vl1[i] = (short)f2bf(xf[8 + i] - bf2f(h));
            }
            *reinterpret_cast<short8*>(&xs_hi[xrow][xc])     = vh0;
            *reinterpret_cast<short8*>(&xs_hi[xrow][xc + 8]) = vh1;
            *reinterpret_cast<short8*>(&xs_lo[xrow][xc])     = vl0;
            *reinterpret_cast<short8*>(&xs_lo[xrow][xc + 8]) = vl1;
            *reinterpret_cast<short8*>(&ws_hi[wcol][wko])      = pwh0;
            *reinterpret_cast<short8*>(&ws_lo[wcol][wko])      = pwl0;
            *reinterpret_cast<short8*>(&ws_hi[wcol + 64][wko]) = pwh1;
            *reinterpret_cast<short8*>(&ws_lo[wcol + 64][wko]) = pwl1;
        }
        __syncthreads();
        if (k0 + 32 < CIN) { loadX(k0 + 32); loadW(k0 + 32); }   // issue next tile early
        int r = lane & 15, ko = (lane >> 4) * 8;
        short8 a_hi[2], a_lo[2];
        #pragma unroll
        for (int rt = 0; rt < 2; ++rt) {
            a_hi[rt] = *reinterpret_cast<const short8*>(&xs_hi[wid * 32 + rt * 16 + r][ko]);
            a_lo[rt] = *reinterpret_cast<const short8*>(&xs_lo[wid * 32 + rt * 16 + r][ko]);
        }
        #pragma unroll
        for (int ct = 0; ct < 8; ++ct) {
            short8 b_hi = *reinterpret_cast<const short8*>(&ws_hi[ct * 16 + r][ko]);
            short8 b_lo = *reinterpret_cast<const short8*>(&ws_lo[ct * 16 + r][ko]);
            #pragma unroll
            for (int rt = 0; rt < 2; ++rt) {
                acc[rt][ct] = __builtin_amdgcn_mfma_f32_16x16x32_bf16(a_hi[rt], b_hi, acc[rt][ct], 0, 0, 0);
                acc[rt][ct] = __builtin_amdgcn_mfma_f32_16x16x32_bf16(a_hi[rt], b_lo, acc[rt][ct], 0, 0, 0);
                acc[rt][ct] = __builtin_amdgcn_mfma_f32_16x16x32_bf16(a_lo[rt], b_hi, acc[rt][ct], 0, 0, 0);
            }
        }
        __syncthreads();
    }
    // epilogue: D row=(lane>>4)*4+j, col=lane&15 per 16x16 tile
    int cl = lane & 15, rg = lane >> 4;
    #pragma unroll
    for (int rt = 0; rt < 2; ++rt) {
        #pragma unroll
        for (int j = 0; j < 4; ++j) {
            int row = row0 + wid * 32 + rt * 16 + rg * 4 + j;
            if (row < NN) {
                unsigned short* hp = Hb + (size_t)row * CH + cl;
                #pragma unroll
                for (int ct = 0; ct < 8; ++ct)
                    hp[ct * 16] = f2bf(acc[rt][ct][j]);
            }
        }
    }
}

// ---------------- in-bucket count + sort -> CSR, row_start, dinv ----------------
// (bucket_scan merged: per-block in-LDS exclusive prefix over cursor totals)

__global__ __launch_bounds__(1024) void bucket_sort(const unsigned int* __restrict__ pairs,
                                                    const int* __restrict__ bucket_cursor,
                                                    int* __restrict__ row_start,
                                                    float* __restrict__ dinv,
                                                    unsigned short* __restrict__ csr_src) {
    __shared__ int bpre[256];
    __shared__ int cnt[256];
    __shared__ int pref[256];
    __shared__ int cur[256];
    int b = blockIdx.x, t = threadIdx.x;
    int p0 = b * BUCKET_CAP;
    int ne = bucket_cursor[b] - p0;

    if (t < 256) {
        int v = (t < NB) ? (bucket_cursor[t] - t * BUCKET_CAP) : 0;
        bpre[t] = v;
    }
    __syncthreads();
    for (int off = 1; off < 256; off <<= 1) {
        int add = (t < 256 && t >= off) ? bpre[t - off] : 0;
        __syncthreads();
        if (t < 256) bpre[t] += add;
        __syncthreads();
    }
    int out0 = (b == 0) ? 0 : bpre[b - 1];

    if (t < 256) cnt[t] = 0;
    __syncthreads();
    for (int i = t; i < ne; i += 1024)
        atomicAdd(&cnt[(pairs[p0 + i] >> 16) & 255], 1);
    __syncthreads();
    if (t < 256) pref[t] = cnt[t];
    __syncthreads();
    for (int off = 1; off < 256; off <<= 1) {
        int add = (t < 256 && t >= off) ? pref[t - off] : 0;
        __syncthreads();
        if (t < 256) pref[t] += add;
        __syncthreads();
    }
    if (t < 256) {
        int n = (b << 8) + t;
        if (n < NN) {
            int rs = out0 + pref[t] - cnt[t];
            row_start[n] = rs;
            cur[t] = rs;
            dinv[n] = rsqrtf((float)(cnt[t] + 1));  // + self-loop
        }
    }
    if (b == NB - 1 && t == 0) row_start[NN] = NE;
    __syncthreads();
    for (int i = t; i < ne; i += 1024) {
        unsigned int p = pairs[p0 + i];
        int pos = atomicAdd(&cur[(p >> 16) & 255], 1);
        csr_src[pos] = (unsigned short)(p & 0xFFFF);
    }
}

// ---------------- MFMA GEMM2: h2 = g1b(bf16) @ W2(hi/lo), bf16 out ----------------
// A is already bf16 (agg1 output) -> no cvt, single xs table, 2 MFMAs/tile.

__global__ __launch_bounds__(256) void gemm2_kernel(const unsigned short* __restrict__ Xb,   // bf16 [NN][128]
                                                    const unsigned short* __restrict__ Wt_hi,
                                                    const unsigned short* __restrict__ Wt_lo,
                                                    unsigned short* __restrict__ Hb) {
    __shared__ unsigned short xs[128][40];
    __shared__ unsigned short ws_hi[64][40];
    __shared__ unsigned short ws_lo[64][40];

    int tid = threadIdx.x;
    int wid = tid >> 6, lane = tid & 63;
    int row0 = blockIdx.x * 128;
    f32x4 acc[2][4] = {};

    for (int k0 = 0; k0 < CH; k0 += 32) {
        {
            int row = tid >> 1, c = (tid & 1) * 16;
            int grow = row0 + row;
            short8 v0, v1;
            if (grow < NN) {
                const short8* p = reinterpret_cast<const short8*>(Xb + (size_t)grow * CH + k0 + c);
                v0 = p[0]; v1 = p[1];
            } else {
                #pragma unroll
                for (int i = 0; i < 8; ++i) { v0[i] = 0; v1[i] = 0; }
            }
            *reinterpret_cast<short8*>(&xs[row][c])     = v0;
            *reinterpret_cast<short8*>(&xs[row][c + 8]) = v1;
        }
        {   // 64 cols x 4 chunks = 256 chunks, 1 per thread
            int col = tid >> 2, ko = (tid & 3) * 8;
            *reinterpret_cast<short8*>(&ws_hi[col][ko]) =
                *reinterpret_cast<const short8*>(Wt_hi + (size_t)col * CH + k0 + ko);
            *reinterpret_cast<short8*>(&ws_lo[col][ko]) =
                *reinterpret_cast<const short8*>(Wt_lo + (size_t)col * CH + k0 + ko);
        }
        __syncthreads();
        int r = lane & 15, ko = (lane >> 4) * 8;
        short8 a[2];
        #pragma unroll
        for (int rt = 0; rt < 2; ++rt)
            a[rt] = *reinterpret_cast<const short8*>(&xs[wid * 32 + rt * 16 + r][ko]);
        #pragma unroll
        for (int ct = 0; ct < 4; ++ct) {
            short8 b_hi = *reinterpret_cast<const short8*>(&ws_hi[ct * 16 + r][ko]);
            short8 b_lo = *reinterpret_cast<const short8*>(&ws_lo[ct * 16 + r][ko]);
            #pragma unroll
            for (int rt = 0; rt < 2; ++rt) {
                acc[rt][ct] = __builtin_amdgcn_mfma_f32_16x16x32_bf16(a[rt], b_hi, acc[rt][ct], 0, 0, 0);
                acc[rt][ct] = __builtin_amdgcn_mfma_f32_16x16x32_bf16(a[rt], b_lo, acc[rt][ct], 0, 0, 0);
            }
        }
        __syncthreads();
    }
    int cl = lane & 15, rg = lane >> 4;
    #pragma unroll
    for (int rt = 0; rt < 2; ++rt) {
        #pragma unroll
        for (int j = 0; j < 4; ++j) {
            int row = row0 + wid * 32 + rt * 16 + rg * 4 + j;
            if (row < NN) {
                unsigned short* hp = Hb + (size_t)row * CO + cl;
                #pragma unroll
                for (int ct = 0; ct < 4; ++ct)
                    hp[ct * 16] = f2bf(acc[rt][ct][j]);
            }
        }
    }
}

// ---------------- CSR gather-aggregation (bf16, 1 wave/node, 8 edges in flight) ----------------
// agg1 now writes bf16x2 g1 (halves its write traffic + gemm2's read traffic).

__global__ __launch_bounds__(64) void agg1_kernel(const unsigned int* __restrict__ H,   // bf16x2, ld=64
                                                  const int* __restrict__ row_start,
                                                  const unsigned short* __restrict__ csr_src,
                                                  const float* __restrict__ dinv,
                                                  const float* __restrict__ bias,
                                                  unsigned int* __restrict__ OUT) {     // bf16x2, ld=64
    int n = blockIdx.x;
    int l = threadIdx.x;                // lane = channel pair {2l, 2l+1}
    float dn = dinv[n];
    unsigned int us = H[n * 64 + l];
    float a0 = dn * bflo(us), a1 = dn * bfhi(us);   // self-loop
    float b0 = 0.f, b1 = 0.f, c0 = 0.f, c1 = 0.f, d0 = 0.f, d1 = 0.f;
    float e0a = 0.f, e1a = 0.f, f0 = 0.f, f1 = 0.f, g0 = 0.f, g1v = 0.f, h0 = 0.f, h1 = 0.f;
    int e0 = row_start[n], e1 = row_start[n + 1];
    for (int base = e0; base < e1; base += 64) {
        int m = min(64, e1 - base);
        int sv = csr_src[base + min(l, m - 1)];
        float wv = (l < m) ? dinv[sv] : 0.f;
        int j = 0;
        for (; j + 8 <= m; j += 8) {    // 8 independent row-gathers in flight
            int s0 = __shfl(sv, j),     s1 = __shfl(sv, j + 1);
            int s2 = __shfl(sv, j + 2), s3 = __shfl(sv, j + 3);
            int s4 = __shfl(sv, j + 4), s5 = __shfl(sv, j + 5);
            int s6 = __shfl(sv, j + 6), s7 = __shfl(sv, j + 7);
            float w0 = __shfl(wv, j),     w1 = __shfl(wv, j + 1);
            float w2 = __shfl(wv, j + 2), w3 = __shfl(wv, j + 3);
            float w4 = __shfl(wv, j + 4), w5 = __shfl(wv, j + 5);
            float w6 = __shfl(wv, j + 6), w7 = __shfl(wv, j + 7);
            unsigned int u0 = H[s0 * 64 + l];
            unsigned int u1 = H[s1 * 64 + l];
            unsigned int u2 = H[s2 * 64 + l];
            unsigned int u3 = H[s3 * 64 + l];
            unsigned int u4 = H[s4 * 64 + l];
            unsigned int u5 = H[s5 * 64 + l];
            unsigned int u6 = H[s6 * 64 + l];
            unsigned int u7 = H[s7 * 64 + l];
            a0  = fmaf(w0, bflo(u0), a0);  a1  = fmaf(w0, bfhi(u0), a1);
            b0  = fmaf(w1, bflo(u1), b0);  b1  = fmaf(w1, bfhi(u1), b1);
            c0  = fmaf(w2, bflo(u2), c0);  c1  = fmaf(w2, bfhi(u2), c1);
            d0  = fmaf(w3, bflo(u3), d0);  d1  = fmaf(w3, bfhi(u3), d1);
            e0a = fmaf(w4, bflo(u4), e0a); e1a = fmaf(w4, bfhi(u4), e1a);
            f0  = fmaf(w5, bflo(u5), f0);  f1  = fmaf(w5, bfhi(u5), f1);
            g0  = fmaf(w6, bflo(u6), g0);  g1v = fmaf(w6, bfhi(u6), g1v);
            h0  = fmaf(w7, bflo(u7), h0);  h1  = fmaf(w7, bfhi(u7), h1);
        }
        for (; j < m; ++j) {
            int s0 = __shfl(sv, j);
            float w0 = __shfl(wv, j);
            unsigned int u0 = H[s0 * 64 + l];
            a0 = fmaf(w0, bflo(u0), a0); a1 = fmaf(w0, bfhi(u0), a1);
        }
    }
    float s0 = ((a0 + b0) + (c0 + d0)) + ((e0a + f0) + (g0 + h0));
    float s1 = ((a1 + b1) + (c1 + d1)) + ((e1a + f1) + (g1v + h1));
    float2 bv = reinterpret_cast<const float2*>(bias)[l];
    float o0 = fmaxf(fmaf(dn, s0, bv.x), 0.f);
    float o1 = fmaxf(fmaf(dn, s1, bv.y), 0.f);
    OUT[(size_t)n * 64 + l] = (unsigned int)f2bf(o0) | ((unsigned int)f2bf(o1) << 16);
}

__global__ __launch_bounds__(64) void agg2_kernel(const unsigned int* __restrict__ H,   // bf16x2, ld=32
                                                  const int* __restrict__ row_start,
                                                  const unsigned short* __restrict__ csr_src,
                                                  const float* __restrict__ dinv,
                                                  const float* __restrict__ bias,
                                                  float* __restrict__ OUT) {
    int n = blockIdx.x;
    int l = threadIdx.x;
    int half = l >> 5;                  // lanes 0-31: even edges, 32-63: odd edges
    int c = l & 31;                     // channel pair {2c, 2c+1}
    float dn = dinv[n];
    unsigned int us = H[n * 32 + c];
    float a0 = half ? 0.f : dn * bflo(us);
    float a1 = half ? 0.f : dn * bfhi(us);
    float b0 = 0.f, b1 = 0.f, c0 = 0.f, c1 = 0.f, d0 = 0.f, d1 = 0.f;
    int e0 = row_start[n], e1 = row_start[n + 1];
    for (int base = e0; base < e1; base += 64) {
        int m = min(64, e1 - base);
        int sv = csr_src[base + min(l, m - 1)];
        float wv = (l < m) ? dinv[sv] : 0.f;
        int j = 0;
        for (; j + 8 <= m; j += 8) {    // per half-wave: 4 edges in flight (8 total)
            int jj0 = j + half, jj1 = j + 2 + half, jj2 = j + 4 + half, jj3 = j + 6 + half;
            int s0 = __shfl(sv, jj0), s1 = __shfl(sv, jj1);
            int s2 = __shfl(sv, jj2), s3 = __shfl(sv, jj3);
            float w0 = __shfl(wv, jj0), w1 = __shfl(wv, jj1);
            float w2 = __shfl(wv, jj2), w3 = __shfl(wv, jj3);
            unsigned int u0 = H[s0 * 32 + c];
            unsigned int u1 = H[s1 * 32 + c];
            unsigned int u2 = H[s2 * 32 + c];
            unsigned int u3 = H[s3 * 32 + c];
            a0 = fmaf(w0, bflo(u0), a0); a1 = fmaf(w0, bfhi(u0), a1);
            b0 = fmaf(w1, bflo(u1), b0); b1 = fmaf(w1, bfhi(u1), b1);
            c0 = fmaf(w2, bflo(u2), c0); c1 = fmaf(w2, bfhi(u2), c1);
            d0 = fmaf(w3, bflo(u3), d0); d1 = fmaf(w3, bfhi(u3), d1);
        }
        for (; j < m; j += 2) {
            int jj = j + half;
            int s = __shfl(sv, min(jj, m - 1));
            float w = __shfl(wv, jj);   // 0 when jj >= m (odd m, half=1)
            unsigned int u = H[s * 32 + c];
            a0 = fmaf(w, bflo(u), a0);
            a1 = fmaf(w, bfhi(u), a1);
        }
    }
    a0 = (a0 + b0) + (c0 + d0);
    a1 = (a1 + b1) + (c1 + d1);
    a0 += __shfl_xor(a0, 32);
    a1 += __shfl_xor(a1, 32);
    if (l < 32) {
        float2 bv = reinterpret_cast<const float2*>(bias)[c];
        float o0 = fmaf(dn, a0, bv.x);
        float o1 = fmaf(dn, a1, bv.y);
        reinterpret_cast<float2*>(OUT)[n * 32 + c] = make_float2(o0, o1);   // no ReLU
    }
}

// ---------------- launch ----------------

extern "C" void kernel_launch(void* const* d_in, const int* in_sizes, int n_in,
                              void* d_out, int out_size, void* d_ws, size_t ws_size,
                              hipStream_t stream) {
    const float* x  = (const float*)d_in[0];
    const int*   ei = (const int*)d_in[1];
    const float* W1 = (const float*)d_in[2];
    const float* b1 = (const float*)d_in[3];
    const float* W2 = (const float*)d_in[4];
    const float* b2 = (const float*)d_in[5];
    const int* srcI = ei;
    const int* dstI = ei + NE;
    float* out = (float*)d_out;

    char* ws = (char*)d_ws;
    size_t off = 0;
    auto take = [&](size_t bytes) {
        char* p = ws + off;
        off = (off + bytes + 255) & ~(size_t)255;
        return p;
    };
    int*            row_start     = (int*)take((size_t)(NN + 1) * 4);
    int*            bucket_cursor = (int*)take((size_t)NB * 4);
    float*          dinv          = (float*)take((size_t)NN * 4);
    unsigned short* W1t_hi        = (unsigned short*)take((size_t)CH * CIN * 2);
    unsigned short* W1t_lo        = (unsigned short*)take((size_t)CH * CIN * 2);
    unsigned short* W2t_hi        = (unsigned short*)take((size_t)CO * CH * 2);
    unsigned short* W2t_lo        = (unsigned short*)take((size_t)CO * CH * 2);
    unsigned short* csr_src       = (unsigned short*)take((size_t)NE * 2);
    unsigned short* h1b           = (unsigned short*)take((size_t)NN * CH * 2);   // bf16
    unsigned short* h2b           = (unsigned short*)take((size_t)NN * CO * 2);   // bf16
    unsigned int*   pairs         = (unsigned int*)take((size_t)NB * BUCKET_CAP * 4); // 12.85 MB
    // g1b (bf16, 12.8 MB) aliases pairs: pairs dead after bucket_sort,
    // before agg1 writes g1b.
    unsigned int*   g1b           = (unsigned int*)pairs;

    wprep<<<(CIN * CH + CH * CO + 255) / 256, 256, 0, stream>>>(W1, W2, W1t_hi, W1t_lo,
                                                                W2t_hi, W2t_lo, bucket_cursor);
    fused_gemm1_scatter<<<SCAT_BLOCKS + G1_TILES, 256, 0, stream>>>(srcI, dstI, bucket_cursor,
                                                                    pairs, x, W1t_hi, W1t_lo, h1b);
    bucket_sort<<<NB, 1024, 0, stream>>>(pairs, bucket_cursor, row_start, dinv, csr_src);

    agg1_kernel<<<NN, 64, 0, stream>>>((const unsigned int*)h1b, row_start, csr_src, dinv, b1, g1b);
    gemm2_kernel<<<G2_TILES, 256, 0, stream>>>((const unsigned short*)g1b, W2t_hi, W2t_lo, h2b);
    agg2_kernel<<<NN, 64, 0, stream>>>((const unsigned int*)h2b, row_start, csr_src, dinv, b2, out);
}